// Round 1
// baseline (294.804 us; speedup 1.0000x reference)
//
#include <hip/hip_runtime.h>
#include <math.h>

#define M_ 3
#define B_ 128
#define T_ 512
#define D_ 1024
#define P_ 256
#define TC 4          // t-chunks for the pooling kernel
#define BM 32
#define BN 64
#define BK 64
#define G  8          // rows per block in gemm2

// ---------------- Kernel 1: partial mean-pool over T ----------------
// grid = M*B*TC blocks, 256 threads. Each block sums T/TC=128 timesteps
// of one (m,b) row, all D=1024 channels (float4 per thread).
__global__ __launch_bounds__(256) void pool_partial(const float* __restrict__ feats,
                                                    float* __restrict__ partial) {
    int blk = blockIdx.x;
    int tc  = blk & (TC - 1);
    int mb  = blk / TC;
    int tid = threadIdx.x;                 // float4 column 0..255
    const int TSTEP = T_ / TC;             // 128
    const float4* src = (const float4*)feats + ((size_t)mb * T_ + (size_t)tc * TSTEP) * (D_ / 4) + tid;
    float4 a0 = make_float4(0.f, 0.f, 0.f, 0.f);
    float4 a1 = a0, a2 = a0, a3 = a0;
    for (int t = 0; t < TSTEP; t += 4) {
        float4 v0 = src[0 * (D_ / 4)];
        float4 v1 = src[1 * (D_ / 4)];
        float4 v2 = src[2 * (D_ / 4)];
        float4 v3 = src[3 * (D_ / 4)];
        src += 4 * (D_ / 4);
        a0.x += v0.x; a0.y += v0.y; a0.z += v0.z; a0.w += v0.w;
        a1.x += v1.x; a1.y += v1.y; a1.z += v1.z; a1.w += v1.w;
        a2.x += v2.x; a2.y += v2.y; a2.z += v2.z; a2.w += v2.w;
        a3.x += v3.x; a3.y += v3.y; a3.z += v3.z; a3.w += v3.w;
    }
    float4 s;
    s.x = (a0.x + a1.x) + (a2.x + a3.x);
    s.y = (a0.y + a1.y) + (a2.y + a3.y);
    s.z = (a0.z + a1.z) + (a2.z + a3.z);
    s.w = (a0.w + a1.w) + (a2.w + a3.w);
    ((float4*)partial)[((size_t)mb * TC + tc) * (D_ / 4) + tid] = s;
}

// ---------------- Kernel 2: finalize pool (sum TC partials, scale) ----------------
__global__ __launch_bounds__(256) void pool_finalize(const float* __restrict__ partial,
                                                     float* __restrict__ pooled) {
    int idx = blockIdx.x * 256 + threadIdx.x;   // float4 index into pooled
    int mb  = idx >> 8;
    int d4  = idx & 255;
    const float4* p4 = (const float4*)partial;
    float4 s = make_float4(0.f, 0.f, 0.f, 0.f);
#pragma unroll
    for (int tc = 0; tc < TC; ++tc) {
        float4 v = p4[((size_t)mb * TC + tc) * (D_ / 4) + d4];
        s.x += v.x; s.y += v.y; s.z += v.z; s.w += v.w;
    }
    const float inv = 1.0f / (float)T_;
    s.x *= inv; s.y *= inv; s.z *= inv; s.w *= inv;
    ((float4*)pooled)[idx] = s;
}

// ---------------- Kernel 3: h = gelu(pooled @ W1 + b1) ----------------
// grid (D/BN, B/BM, M), 256 threads. LDS-tiled fp32 GEMM.
__global__ __launch_bounds__(256) void gemm1_gelu(const float* __restrict__ pooled,
                                                  const float* __restrict__ W1,
                                                  const float* __restrict__ b1,
                                                  float* __restrict__ h) {
    __shared__ float As[BM][BK + 1];   // +1 pad: broadcast-friendly reads
    __shared__ float Bs[BK][BN];
    int m  = blockIdx.z;
    int b0 = blockIdx.y * BM;
    int e0 = blockIdx.x * BN;
    int tid = threadIdx.x;
    int tx = tid & 31;        // 0..31 -> col
    int ty = tid >> 5;        // 0..7  -> row group
    int ar  = tid >> 4;       // 0..15 staging row
    int ac4 = tid & 15;       // 0..15 staging float4 col

    const float* Abase = pooled + ((size_t)m * B_ + b0) * D_;
    const float* Bbase = W1 + (size_t)m * D_ * D_ + e0;

    float acc[4][2] = {{0.f, 0.f}, {0.f, 0.f}, {0.f, 0.f}, {0.f, 0.f}};

    for (int k0 = 0; k0 < D_; k0 += BK) {
        float4 av0 = *(const float4*)(Abase + (size_t)ar * D_ + k0 + ac4 * 4);
        float4 av1 = *(const float4*)(Abase + (size_t)(ar + 16) * D_ + k0 + ac4 * 4);
        float4 bv0 = *(const float4*)(Bbase + (size_t)(k0 + ar) * D_ + ac4 * 4);
        float4 bv1 = *(const float4*)(Bbase + (size_t)(k0 + ar + 16) * D_ + ac4 * 4);
        float4 bv2 = *(const float4*)(Bbase + (size_t)(k0 + ar + 32) * D_ + ac4 * 4);
        float4 bv3 = *(const float4*)(Bbase + (size_t)(k0 + ar + 48) * D_ + ac4 * 4);
        __syncthreads();   // previous iteration's compute done
        As[ar][ac4 * 4 + 0] = av0.x; As[ar][ac4 * 4 + 1] = av0.y;
        As[ar][ac4 * 4 + 2] = av0.z; As[ar][ac4 * 4 + 3] = av0.w;
        As[ar + 16][ac4 * 4 + 0] = av1.x; As[ar + 16][ac4 * 4 + 1] = av1.y;
        As[ar + 16][ac4 * 4 + 2] = av1.z; As[ar + 16][ac4 * 4 + 3] = av1.w;
        *(float4*)&Bs[ar][ac4 * 4]      = bv0;
        *(float4*)&Bs[ar + 16][ac4 * 4] = bv1;
        *(float4*)&Bs[ar + 32][ac4 * 4] = bv2;
        *(float4*)&Bs[ar + 48][ac4 * 4] = bv3;
        __syncthreads();
#pragma unroll 16
        for (int k = 0; k < BK; ++k) {
            float a0 = As[ty][k];
            float a1 = As[ty + 8][k];
            float a2 = As[ty + 16][k];
            float a3 = As[ty + 24][k];
            float bb0 = Bs[k][tx];
            float bb1 = Bs[k][tx + 32];
            acc[0][0] += a0 * bb0; acc[0][1] += a0 * bb1;
            acc[1][0] += a1 * bb0; acc[1][1] += a1 * bb1;
            acc[2][0] += a2 * bb0; acc[2][1] += a2 * bb1;
            acc[3][0] += a3 * bb0; acc[3][1] += a3 * bb1;
        }
    }
#pragma unroll
    for (int i = 0; i < 4; ++i) {
        int row = b0 + ty + 8 * i;
#pragma unroll
        for (int c = 0; c < 2; ++c) {
            int col = e0 + tx + 32 * c;
            float x = acc[i][c] + b1[m * D_ + col];
            float gx = 0.5f * x * (1.0f + erff(x * 0.70710678118654752f));
            h[((size_t)m * B_ + row) * D_ + col] = gx;
        }
    }
}

// ---------------- Kernel 4: z = h @ W2 + b2, LayerNorm, L2-normalize ----------------
// grid (B/G, M), 256 threads (= P). Each block: G=8 batch rows.
__global__ __launch_bounds__(256) void gemm2_ln(const float* __restrict__ h,
                                                const float* __restrict__ W2,
                                                const float* __restrict__ b2,
                                                const float* __restrict__ gamma,
                                                const float* __restrict__ beta,
                                                float* __restrict__ out) {
    int m  = blockIdx.y;
    int b0 = blockIdx.x * G;
    int tid = threadIdx.x;              // output channel p
    int lane = tid & 63, w = tid >> 6;

    __shared__ float red1[4][G];
    __shared__ float red2[4][G];

    const float* W2base = W2 + (size_t)m * D_ * P_ + tid;
    const float* hbase  = h + ((size_t)m * B_ + b0) * D_;

    float acc[G];
#pragma unroll
    for (int g = 0; g < G; ++g) acc[g] = 0.f;

    for (int k4 = 0; k4 < D_ / 4; ++k4) {
        float w0 = W2base[(size_t)(4 * k4 + 0) * P_];
        float w1 = W2base[(size_t)(4 * k4 + 1) * P_];
        float w2 = W2base[(size_t)(4 * k4 + 2) * P_];
        float w3 = W2base[(size_t)(4 * k4 + 3) * P_];
#pragma unroll
        for (int g = 0; g < G; ++g) {
            float4 hv = *(const float4*)(hbase + (size_t)g * D_ + 4 * k4);  // uniform -> s_load
            acc[g] += hv.x * w0 + hv.y * w1 + hv.z * w2 + hv.w * w3;
        }
    }

    float bias = b2[m * P_ + tid];
    float gm   = gamma[m * P_ + tid];
    float bt   = beta[m * P_ + tid];

    float z[G];
#pragma unroll
    for (int g = 0; g < G; ++g) z[g] = acc[g] + bias;

    // LN reductions: per-row mean and mean of squares across 256 threads
#pragma unroll
    for (int g = 0; g < G; ++g) {
        float s1 = z[g], s2 = z[g] * z[g];
        for (int off = 32; off > 0; off >>= 1) {
            s1 += __shfl_xor(s1, off);
            s2 += __shfl_xor(s2, off);
        }
        if (lane == 0) { red1[w][g] = s1; red2[w][g] = s2; }
    }
    __syncthreads();
#pragma unroll
    for (int g = 0; g < G; ++g) {
        float s1 = (red1[0][g] + red1[1][g]) + (red1[2][g] + red1[3][g]);
        float s2 = (red2[0][g] + red2[1][g]) + (red2[2][g] + red2[3][g]);
        float mu  = s1 * (1.0f / P_);
        float var = s2 * (1.0f / P_) - mu * mu;
        float inv = 1.0f / sqrtf(var + 1e-5f);
        z[g] = (z[g] - mu) * inv * gm + bt;
    }
    __syncthreads();   // red buffers reused below

    // L2 norm across P
#pragma unroll
    for (int g = 0; g < G; ++g) {
        float s = z[g] * z[g];
        for (int off = 32; off > 0; off >>= 1) s += __shfl_xor(s, off);
        if (lane == 0) red1[w][g] = s;
    }
    __syncthreads();
#pragma unroll
    for (int g = 0; g < G; ++g) {
        float s = (red1[0][g] + red1[1][g]) + (red1[2][g] + red1[3][g]);
        float n = sqrtf(s);
        out[((size_t)m * B_ + b0 + g) * P_ + tid] = z[g] / fmaxf(n, 1e-12f);
    }
}

extern "C" void kernel_launch(void* const* d_in, const int* in_sizes, int n_in,
                              void* d_out, int out_size, void* d_ws, size_t ws_size,
                              hipStream_t stream) {
    const float* feats = (const float*)d_in[0];
    const float* W1    = (const float*)d_in[1];
    const float* b1    = (const float*)d_in[2];
    const float* W2    = (const float*)d_in[3];
    const float* b2    = (const float*)d_in[4];
    const float* gamma = (const float*)d_in[5];
    const float* beta  = (const float*)d_in[6];
    float* out = (float*)d_out;

    float* wsf     = (float*)d_ws;
    float* partial = wsf;                                  // M*B*TC*D = 1,572,864 floats
    float* pooled  = wsf + (size_t)M_ * B_ * TC * D_;      // M*B*D = 393,216 floats
    float* hbuf    = pooled + (size_t)M_ * B_ * D_;        // M*B*D = 393,216 floats
    // total ws: 9,437,184 bytes

    pool_partial<<<M_ * B_ * TC, 256, 0, stream>>>(feats, partial);
    pool_finalize<<<(M_ * B_ * D_ / 4) / 256, 256, 0, stream>>>(partial, pooled);
    dim3 g3(D_ / BN, B_ / BM, M_);
    gemm1_gelu<<<g3, 256, 0, stream>>>(pooled, W1, b1, hbuf);
    dim3 g4(B_ / G, M_);
    gemm2_ln<<<g4, 256, 0, stream>>>(hbuf, W2, b2, gamma, beta, out);
}

// Round 2
// 219.629 us; speedup vs baseline: 1.3423x; 1.3423x over previous
//
#include <hip/hip_runtime.h>
#include <math.h>

#define M_ 3
#define B_ 128
#define T_ 512
#define D_ 1024
#define P_ 256
#define TC 4          // t-chunks for the pooling kernel
#define BM1 32
#define BN1 64
#define BK1 64
#define LDA1 (BK1 + 4)   // As row stride: 68 floats -> 272B, 16B-aligned, distinct banks per row
#define G  2          // rows per block in gemm2

// ---------------- Kernel 1: partial mean-pool over T ----------------
// grid = M*B*TC blocks, 256 threads. Each block sums T/TC=128 timesteps
// of one (m,b) row, all D=1024 channels (float4 per thread).
__global__ __launch_bounds__(256) void pool_partial(const float* __restrict__ feats,
                                                    float* __restrict__ partial) {
    int blk = blockIdx.x;
    int tc  = blk & (TC - 1);
    int mb  = blk / TC;
    int tid = threadIdx.x;                 // float4 column 0..255
    const int TSTEP = T_ / TC;             // 128
    const float4* src = (const float4*)feats + ((size_t)mb * T_ + (size_t)tc * TSTEP) * (D_ / 4) + tid;
    float4 a0 = make_float4(0.f, 0.f, 0.f, 0.f);
    float4 a1 = a0, a2 = a0, a3 = a0;
    for (int t = 0; t < TSTEP; t += 4) {
        float4 v0 = src[0 * (D_ / 4)];
        float4 v1 = src[1 * (D_ / 4)];
        float4 v2 = src[2 * (D_ / 4)];
        float4 v3 = src[3 * (D_ / 4)];
        src += 4 * (D_ / 4);
        a0.x += v0.x; a0.y += v0.y; a0.z += v0.z; a0.w += v0.w;
        a1.x += v1.x; a1.y += v1.y; a1.z += v1.z; a1.w += v1.w;
        a2.x += v2.x; a2.y += v2.y; a2.z += v2.z; a2.w += v2.w;
        a3.x += v3.x; a3.y += v3.y; a3.z += v3.z; a3.w += v3.w;
    }
    float4 s;
    s.x = (a0.x + a1.x) + (a2.x + a3.x);
    s.y = (a0.y + a1.y) + (a2.y + a3.y);
    s.z = (a0.z + a1.z) + (a2.z + a3.z);
    s.w = (a0.w + a1.w) + (a2.w + a3.w);
    ((float4*)partial)[((size_t)mb * TC + tc) * (D_ / 4) + tid] = s;
}

// ---------------- Kernel 2: finalize pool (sum TC partials, scale) ----------------
__global__ __launch_bounds__(256) void pool_finalize(const float* __restrict__ partial,
                                                     float* __restrict__ pooled) {
    int idx = blockIdx.x * 256 + threadIdx.x;   // float4 index into pooled
    int mb  = idx >> 8;
    int d4  = idx & 255;
    const float4* p4 = (const float4*)partial;
    float4 s = make_float4(0.f, 0.f, 0.f, 0.f);
#pragma unroll
    for (int tc = 0; tc < TC; ++tc) {
        float4 v = p4[((size_t)mb * TC + tc) * (D_ / 4) + d4];
        s.x += v.x; s.y += v.y; s.z += v.z; s.w += v.w;
    }
    const float inv = 1.0f / (float)T_;
    s.x *= inv; s.y *= inv; s.z *= inv; s.w *= inv;
    ((float4*)pooled)[idx] = s;
}

// ---------------- Kernel 3: h = gelu(pooled @ W1 + b1) ----------------
// grid (D/BN1=16, B/BM1=4, M) = 192 blocks, 256 threads.
// Micro-tile 2 rows x 4 cols: per k, 2 broadcast b32 A reads (conflict-free
// via +4 pad) + 1 ds_read_b128 B read feeding 8 FMAs (2 B/FLOP LDS traffic).
__global__ __launch_bounds__(256) void gemm1_gelu(const float* __restrict__ pooled,
                                                  const float* __restrict__ W1,
                                                  const float* __restrict__ b1,
                                                  float* __restrict__ h) {
    __shared__ float As[BM1][LDA1];
    __shared__ float Bs[BK1][BN1];
    int m  = blockIdx.z;
    int b0 = blockIdx.y * BM1;
    int e0 = blockIdx.x * BN1;
    int tid = threadIdx.x;
    int ar  = tid >> 4;       // 0..15 staging row
    int ac4 = tid & 15;       // 0..15 staging float4 col
    int ty  = tid >> 4;       // 0..15 -> rows 2ty, 2ty+1
    int tx  = tid & 15;       // 0..15 -> cols tx*4..+3

    const float* Abase = pooled + ((size_t)m * B_ + b0) * D_;
    const float* Bbase = W1 + (size_t)m * D_ * D_ + e0;

    float4 acc0 = make_float4(0.f, 0.f, 0.f, 0.f);
    float4 acc1 = make_float4(0.f, 0.f, 0.f, 0.f);

    for (int k0 = 0; k0 < D_; k0 += BK1) {
        float4 av0 = *(const float4*)(Abase + (size_t)ar * D_ + k0 + ac4 * 4);
        float4 av1 = *(const float4*)(Abase + (size_t)(ar + 16) * D_ + k0 + ac4 * 4);
        float4 bv0 = *(const float4*)(Bbase + (size_t)(k0 + ar) * D_ + ac4 * 4);
        float4 bv1 = *(const float4*)(Bbase + (size_t)(k0 + ar + 16) * D_ + ac4 * 4);
        float4 bv2 = *(const float4*)(Bbase + (size_t)(k0 + ar + 32) * D_ + ac4 * 4);
        float4 bv3 = *(const float4*)(Bbase + (size_t)(k0 + ar + 48) * D_ + ac4 * 4);
        __syncthreads();   // previous iteration's compute done
        *(float4*)&As[ar][ac4 * 4]      = av0;
        *(float4*)&As[ar + 16][ac4 * 4] = av1;
        *(float4*)&Bs[ar][ac4 * 4]      = bv0;
        *(float4*)&Bs[ar + 16][ac4 * 4] = bv1;
        *(float4*)&Bs[ar + 32][ac4 * 4] = bv2;
        *(float4*)&Bs[ar + 48][ac4 * 4] = bv3;
        __syncthreads();
#pragma unroll
        for (int k = 0; k < BK1; ++k) {
            float a0 = As[2 * ty][k];
            float a1 = As[2 * ty + 1][k];
            float4 b = *(float4*)&Bs[k][tx * 4];
            acc0.x += a0 * b.x; acc0.y += a0 * b.y; acc0.z += a0 * b.z; acc0.w += a0 * b.w;
            acc1.x += a1 * b.x; acc1.y += a1 * b.y; acc1.z += a1 * b.z; acc1.w += a1 * b.w;
        }
    }
    int col = e0 + tx * 4;
    float4 bb = *(const float4*)(b1 + m * D_ + col);
    float4 z0, z1;
    z0.x = acc0.x + bb.x; z0.y = acc0.y + bb.y; z0.z = acc0.z + bb.z; z0.w = acc0.w + bb.w;
    z1.x = acc1.x + bb.x; z1.y = acc1.y + bb.y; z1.z = acc1.z + bb.z; z1.w = acc1.w + bb.w;
    const float is2 = 0.70710678118654752f;
    float4 g0, g1;
    g0.x = 0.5f * z0.x * (1.0f + erff(z0.x * is2));
    g0.y = 0.5f * z0.y * (1.0f + erff(z0.y * is2));
    g0.z = 0.5f * z0.z * (1.0f + erff(z0.z * is2));
    g0.w = 0.5f * z0.w * (1.0f + erff(z0.w * is2));
    g1.x = 0.5f * z1.x * (1.0f + erff(z1.x * is2));
    g1.y = 0.5f * z1.y * (1.0f + erff(z1.y * is2));
    g1.z = 0.5f * z1.z * (1.0f + erff(z1.z * is2));
    g1.w = 0.5f * z1.w * (1.0f + erff(z1.w * is2));
    int row0 = b0 + 2 * ty;
    *(float4*)&h[((size_t)m * B_ + row0) * D_ + col]     = g0;
    *(float4*)&h[((size_t)m * B_ + row0 + 1) * D_ + col] = g1;
}

// ---------------- Kernel 4: z = h @ W2 + b2, LayerNorm, L2-normalize ----------------
// grid (B/G=64, M) = 192 blocks, 256 threads (= P). Each block: G=2 batch rows.
__global__ __launch_bounds__(256) void gemm2_ln(const float* __restrict__ h,
                                                const float* __restrict__ W2,
                                                const float* __restrict__ b2,
                                                const float* __restrict__ gamma,
                                                const float* __restrict__ beta,
                                                float* __restrict__ out) {
    int m  = blockIdx.y;
    int b0 = blockIdx.x * G;
    int tid = threadIdx.x;              // output channel p
    int lane = tid & 63, w = tid >> 6;

    __shared__ float red1[4][G];
    __shared__ float red2[4][G];

    const float* W2base = W2 + (size_t)m * D_ * P_ + tid;
    const float* hbase  = h + ((size_t)m * B_ + b0) * D_;

    float acc[G];
#pragma unroll
    for (int g = 0; g < G; ++g) acc[g] = 0.f;

#pragma unroll 4
    for (int k4 = 0; k4 < D_ / 4; ++k4) {
        float w0 = W2base[(size_t)(4 * k4 + 0) * P_];
        float w1 = W2base[(size_t)(4 * k4 + 1) * P_];
        float w2 = W2base[(size_t)(4 * k4 + 2) * P_];
        float w3 = W2base[(size_t)(4 * k4 + 3) * P_];
#pragma unroll
        for (int g = 0; g < G; ++g) {
            float4 hv = *(const float4*)(hbase + (size_t)g * D_ + 4 * k4);  // uniform addr
            acc[g] += hv.x * w0 + hv.y * w1 + hv.z * w2 + hv.w * w3;
        }
    }

    float bias = b2[m * P_ + tid];
    float gm   = gamma[m * P_ + tid];
    float bt   = beta[m * P_ + tid];

    float z[G];
#pragma unroll
    for (int g = 0; g < G; ++g) z[g] = acc[g] + bias;

    // LN reductions: per-row mean and mean of squares across 256 threads
#pragma unroll
    for (int g = 0; g < G; ++g) {
        float s1 = z[g], s2 = z[g] * z[g];
        for (int off = 32; off > 0; off >>= 1) {
            s1 += __shfl_xor(s1, off);
            s2 += __shfl_xor(s2, off);
        }
        if (lane == 0) { red1[w][g] = s1; red2[w][g] = s2; }
    }
    __syncthreads();
#pragma unroll
    for (int g = 0; g < G; ++g) {
        float s1 = (red1[0][g] + red1[1][g]) + (red1[2][g] + red1[3][g]);
        float s2 = (red2[0][g] + red2[1][g]) + (red2[2][g] + red2[3][g]);
        float mu  = s1 * (1.0f / P_);
        float var = s2 * (1.0f / P_) - mu * mu;
        float inv = 1.0f / sqrtf(var + 1e-5f);
        z[g] = (z[g] - mu) * inv * gm + bt;
    }
    __syncthreads();   // red buffers reused below

    // L2 norm across P
#pragma unroll
    for (int g = 0; g < G; ++g) {
        float s = z[g] * z[g];
        for (int off = 32; off > 0; off >>= 1) s += __shfl_xor(s, off);
        if (lane == 0) red1[w][g] = s;
    }
    __syncthreads();
#pragma unroll
    for (int g = 0; g < G; ++g) {
        float s = (red1[0][g] + red1[1][g]) + (red1[2][g] + red1[3][g]);
        float n = sqrtf(s);
        out[((size_t)m * B_ + b0 + g) * P_ + tid] = z[g] / fmaxf(n, 1e-12f);
    }
}

extern "C" void kernel_launch(void* const* d_in, const int* in_sizes, int n_in,
                              void* d_out, int out_size, void* d_ws, size_t ws_size,
                              hipStream_t stream) {
    const float* feats = (const float*)d_in[0];
    const float* W1    = (const float*)d_in[1];
    const float* b1    = (const float*)d_in[2];
    const float* W2    = (const float*)d_in[3];
    const float* b2    = (const float*)d_in[4];
    const float* gamma = (const float*)d_in[5];
    const float* beta  = (const float*)d_in[6];
    float* out = (float*)d_out;

    float* wsf     = (float*)d_ws;
    float* partial = wsf;                                  // M*B*TC*D = 1,572,864 floats
    float* pooled  = wsf + (size_t)M_ * B_ * TC * D_;      // M*B*D = 393,216 floats
    float* hbuf    = pooled + (size_t)M_ * B_ * D_;        // M*B*D = 393,216 floats
    // total ws: 9,437,184 bytes

    pool_partial<<<M_ * B_ * TC, 256, 0, stream>>>(feats, partial);
    pool_finalize<<<(M_ * B_ * D_ / 4) / 256, 256, 0, stream>>>(partial, pooled);
    dim3 g3(D_ / BN1, B_ / BM1, M_);
    gemm1_gelu<<<g3, 256, 0, stream>>>(pooled, W1, b1, hbuf);
    dim3 g4(B_ / G, M_);
    gemm2_ln<<<g4, 256, 0, stream>>>(hbuf, W2, b2, gamma, beta, out);
}

// Round 3
// 190.541 us; speedup vs baseline: 1.5472x; 1.1527x over previous
//
#include <hip/hip_runtime.h>
#include <math.h>

#define M_ 3
#define B_ 128
#define T_ 512
#define D_ 1024
#define P_ 256
#define TC 2            // t-chunks for the pooling kernel (768 blocks = 3/CU exact)
#define NRIDER 64       // W2-cast rider blocks inside pool kernel
#define BM1 32
#define BN1 64

// bf16 round-to-nearest-even from f32 bits
__device__ __forceinline__ unsigned int f2bf(float f) {
    unsigned int x = __float_as_uint(f);
    return (x + 0x7fffu + ((x >> 16) & 1u)) >> 16;
}

// ---------------- Kernel 1: pool partials (TC=2) + W2->packed-bf16 cast riders ----------------
// blocks [0, NRIDER): cast W2 (f32 [M][D][P]) to packed pairs w2p (u32 [M][D/2][P]).
// blocks [NRIDER, NRIDER+M*B*TC): sum 256 timesteps of one (m,b) row into partial.
__global__ __launch_bounds__(256) void pool_and_cast(const float* __restrict__ feats,
                                                     const float* __restrict__ W2,
                                                     float* __restrict__ partial,
                                                     unsigned int* __restrict__ w2p) {
    int blk = blockIdx.x;
    int tid = threadIdx.x;
    if (blk < NRIDER) {
        // w2p[m][k2][p] = bf16(W2[m][2k2][p]) | bf16(W2[m][2k2+1][p])<<16
        const int TOT = M_ * (D_ / 2) * P_;          // 393216
        for (int i = blk * 256 + tid; i < TOT; i += NRIDER * 256) {
            int p  = i & (P_ - 1);
            int k2 = (i >> 8) & (D_ / 2 - 1);
            int m  = i >> 17;
            size_t base = (size_t)m * D_ * P_ + (size_t)(2 * k2) * P_ + p;
            float f0 = W2[base];
            float f1 = W2[base + P_];
            w2p[i] = f2bf(f0) | (f2bf(f1) << 16);
        }
        return;
    }
    blk -= NRIDER;
    int tc = blk & (TC - 1);
    int mb = blk / TC;
    const int TSTEP = T_ / TC;                       // 256
    const float4* src = (const float4*)feats + ((size_t)mb * T_ + (size_t)tc * TSTEP) * (D_ / 4) + tid;
    float4 a0 = make_float4(0.f, 0.f, 0.f, 0.f);
    float4 a1 = a0, a2 = a0, a3 = a0, a4 = a0, a5 = a0, a6 = a0, a7 = a0;
    for (int t = 0; t < TSTEP; t += 8) {
        float4 v0 = src[0 * (D_ / 4)];
        float4 v1 = src[1 * (D_ / 4)];
        float4 v2 = src[2 * (D_ / 4)];
        float4 v3 = src[3 * (D_ / 4)];
        float4 v4 = src[4 * (D_ / 4)];
        float4 v5 = src[5 * (D_ / 4)];
        float4 v6 = src[6 * (D_ / 4)];
        float4 v7 = src[7 * (D_ / 4)];
        src += 8 * (D_ / 4);
        a0.x += v0.x; a0.y += v0.y; a0.z += v0.z; a0.w += v0.w;
        a1.x += v1.x; a1.y += v1.y; a1.z += v1.z; a1.w += v1.w;
        a2.x += v2.x; a2.y += v2.y; a2.z += v2.z; a2.w += v2.w;
        a3.x += v3.x; a3.y += v3.y; a3.z += v3.z; a3.w += v3.w;
        a4.x += v4.x; a4.y += v4.y; a4.z += v4.z; a4.w += v4.w;
        a5.x += v5.x; a5.y += v5.y; a5.z += v5.z; a5.w += v5.w;
        a6.x += v6.x; a6.y += v6.y; a6.z += v6.z; a6.w += v6.w;
        a7.x += v7.x; a7.y += v7.y; a7.z += v7.z; a7.w += v7.w;
    }
    float4 s;
    s.x = ((a0.x + a1.x) + (a2.x + a3.x)) + ((a4.x + a5.x) + (a6.x + a7.x));
    s.y = ((a0.y + a1.y) + (a2.y + a3.y)) + ((a4.y + a5.y) + (a6.y + a7.y));
    s.z = ((a0.z + a1.z) + (a2.z + a3.z)) + ((a4.z + a5.z) + (a6.z + a7.z));
    s.w = ((a0.w + a1.w) + (a2.w + a3.w)) + ((a4.w + a5.w) + (a6.w + a7.w));
    ((float4*)partial)[((size_t)mb * TC + tc) * (D_ / 4) + tid] = s;
}

// ---------------- Kernel 2: h = gelu(mean(partial) @ W1 + b1), split-K x2, 512 thr ----------------
// grid (D/BN1=16, B/BM1=4, M) = 192 blocks. half = tid>>8 owns K in [half*512, half*512+512).
__global__ __launch_bounds__(512) void gemm1_gelu(const float* __restrict__ partial,
                                                  const float* __restrict__ W1,
                                                  const float* __restrict__ b1,
                                                  float* __restrict__ h) {
    __shared__ float As[2][BM1][68];   // stride 68: 272B rows, 16B-aligned, conflict-free
    __shared__ float Bs[2][64][68];
    int m  = blockIdx.z;
    int b0 = blockIdx.y * BM1;
    int e0 = blockIdx.x * BN1;
    int tid  = threadIdx.x;
    int half = tid >> 8;
    int t    = tid & 255;
    int ar  = t >> 4;        // 0..15
    int ac4 = t & 15;        // 0..15
    int ty  = t >> 4;        // rows 2ty, 2ty+1
    int tx  = t & 15;        // cols 4tx..4tx+3

    const float* Ab = partial + (size_t)(m * B_ + b0) * TC * D_;
    const float* Bb = W1 + (size_t)m * D_ * D_ + e0;
    const float inv = 1.0f / (float)T_;

    float4 acc0 = make_float4(0.f, 0.f, 0.f, 0.f);
    float4 acc1 = make_float4(0.f, 0.f, 0.f, 0.f);

    for (int kk = 0; kk < 8; ++kk) {
        int k0 = half * 512 + kk * 64;
        const float* Ar0 = Ab + (size_t)(TC * ar) * D_ + k0 + 4 * ac4;
        const float* Ar1 = Ab + (size_t)(TC * (ar + 16)) * D_ + k0 + 4 * ac4;
        float4 p00 = *(const float4*)(Ar0);
        float4 p01 = *(const float4*)(Ar0 + D_);
        float4 p10 = *(const float4*)(Ar1);
        float4 p11 = *(const float4*)(Ar1 + D_);
        float4 bv0 = *(const float4*)(Bb + (size_t)(k0 + ar) * D_ + 4 * ac4);
        float4 bv1 = *(const float4*)(Bb + (size_t)(k0 + ar + 16) * D_ + 4 * ac4);
        float4 bv2 = *(const float4*)(Bb + (size_t)(k0 + ar + 32) * D_ + 4 * ac4);
        float4 bv3 = *(const float4*)(Bb + (size_t)(k0 + ar + 48) * D_ + 4 * ac4);
        __syncthreads();   // previous iteration's reads done
        float4 av0, av1;
        av0.x = (p00.x + p01.x) * inv; av0.y = (p00.y + p01.y) * inv;
        av0.z = (p00.z + p01.z) * inv; av0.w = (p00.w + p01.w) * inv;
        av1.x = (p10.x + p11.x) * inv; av1.y = (p10.y + p11.y) * inv;
        av1.z = (p10.z + p11.z) * inv; av1.w = (p10.w + p11.w) * inv;
        *(float4*)&As[half][ar][4 * ac4]      = av0;
        *(float4*)&As[half][ar + 16][4 * ac4] = av1;
        *(float4*)&Bs[half][ar][4 * ac4]      = bv0;
        *(float4*)&Bs[half][ar + 16][4 * ac4] = bv1;
        *(float4*)&Bs[half][ar + 32][4 * ac4] = bv2;
        *(float4*)&Bs[half][ar + 48][4 * ac4] = bv3;
        __syncthreads();
#pragma unroll
        for (int k = 0; k < 64; ++k) {
            float A0 = As[half][2 * ty][k];
            float A1 = As[half][2 * ty + 1][k];
            float4 bb = *(const float4*)&Bs[half][k][4 * tx];
            acc0.x += A0 * bb.x; acc0.y += A0 * bb.y; acc0.z += A0 * bb.z; acc0.w += A0 * bb.w;
            acc1.x += A1 * bb.x; acc1.y += A1 * bb.y; acc1.z += A1 * bb.z; acc1.w += A1 * bb.w;
        }
    }
    __syncthreads();   // all inner reads done; reuse As[0] as reduction buffer
    float* zb = &As[0][0][0];   // [32][68]
    if (half == 0) {
        *(float4*)&zb[(2 * ty) * 68 + 4 * tx]     = acc0;
        *(float4*)&zb[(2 * ty + 1) * 68 + 4 * tx] = acc1;
    }
    __syncthreads();
    if (half == 1) {
        int col = e0 + 4 * tx;
        float4 bb = *(const float4*)(b1 + m * D_ + col);
        float4 z0 = *(const float4*)&zb[(2 * ty) * 68 + 4 * tx];
        float4 z1 = *(const float4*)&zb[(2 * ty + 1) * 68 + 4 * tx];
        z0.x += acc0.x + bb.x; z0.y += acc0.y + bb.y; z0.z += acc0.z + bb.z; z0.w += acc0.w + bb.w;
        z1.x += acc1.x + bb.x; z1.y += acc1.y + bb.y; z1.z += acc1.z + bb.z; z1.w += acc1.w + bb.w;
        const float is2 = 0.70710678118654752f;
        float4 g0, g1;
        g0.x = 0.5f * z0.x * (1.0f + erff(z0.x * is2));
        g0.y = 0.5f * z0.y * (1.0f + erff(z0.y * is2));
        g0.z = 0.5f * z0.z * (1.0f + erff(z0.z * is2));
        g0.w = 0.5f * z0.w * (1.0f + erff(z0.w * is2));
        g1.x = 0.5f * z1.x * (1.0f + erff(z1.x * is2));
        g1.y = 0.5f * z1.y * (1.0f + erff(z1.y * is2));
        g1.z = 0.5f * z1.z * (1.0f + erff(z1.z * is2));
        g1.w = 0.5f * z1.w * (1.0f + erff(z1.w * is2));
        int row0 = b0 + 2 * ty;
        *(float4*)&h[((size_t)m * B_ + row0) * D_ + col]     = g0;
        *(float4*)&h[((size_t)m * B_ + row0 + 1) * D_ + col] = g1;
    }
}

// ---------------- Kernel 3: z = h @ W2 + b2, LN, L2-normalize; split-K x2, 512 thr ----------------
// grid (B/2=64, M) = 192 blocks. p = tid&255 (output col), half = tid>>8 (K-half).
__global__ __launch_bounds__(512) void gemm2_ln(const float* __restrict__ h,
                                                const unsigned int* __restrict__ w2p,
                                                const float* __restrict__ b2,
                                                const float* __restrict__ gamma,
                                                const float* __restrict__ beta,
                                                float* __restrict__ out) {
    int m  = blockIdx.y;
    int b0 = blockIdx.x * 2;
    int tid  = threadIdx.x;
    int p    = tid & 255;
    int half = tid >> 8;
    int lane = tid & 63;
    int w    = (tid >> 6) & 3;   // wave index within the 4-wave row group

    __shared__ float accs[2][2][256];   // [half][row][p]
    __shared__ float redA[2][4];
    __shared__ float redB[2][4];
    __shared__ float redC[2][4];

    const unsigned int* Wp = w2p + (size_t)m * (D_ / 2) * P_ + (size_t)half * 256 * P_ + p;
    const float* hb = h + ((size_t)m * B_ + b0) * D_ + half * 512;

    float acc0 = 0.f, acc1 = 0.f;
#pragma unroll 4
    for (int q = 0; q < 128; ++q) {
        unsigned int u0 = Wp[(size_t)(2 * q) * P_];
        unsigned int u1 = Wp[(size_t)(2 * q + 1) * P_];
        float w0 = __uint_as_float(u0 << 16);
        float w1 = __uint_as_float(u0 & 0xffff0000u);
        float w2 = __uint_as_float(u1 << 16);
        float w3 = __uint_as_float(u1 & 0xffff0000u);
        float4 h0 = *(const float4*)(hb + 4 * q);          // row b0, broadcast
        float4 h1 = *(const float4*)(hb + D_ + 4 * q);     // row b0+1, broadcast
        acc0 += h0.x * w0 + h0.y * w1 + h0.z * w2 + h0.w * w3;
        acc1 += h1.x * w0 + h1.y * w1 + h1.z * w2 + h1.w * w3;
    }
    accs[half][0][p] = acc0;
    accs[half][1][p] = acc1;
    __syncthreads();

    // epilogue: thread (g = half, p) owns output element (row b0+g, col p)
    int g = half;
    float z = accs[0][g][p] + accs[1][g][p] + b2[m * P_ + p];

    // LN stats across the 256 p's of row g (threads tid in [g*256, g*256+256) = waves 4g..4g+3)
    float s1 = z, s2 = z * z;
    for (int off = 32; off > 0; off >>= 1) {
        s1 += __shfl_xor(s1, off);
        s2 += __shfl_xor(s2, off);
    }
    if (lane == 0) { redA[g][w] = s1; redB[g][w] = s2; }
    __syncthreads();
    s1 = (redA[g][0] + redA[g][1]) + (redA[g][2] + redA[g][3]);
    s2 = (redB[g][0] + redB[g][1]) + (redB[g][2] + redB[g][3]);
    float mu  = s1 * (1.0f / P_);
    float var = s2 * (1.0f / P_) - mu * mu;
    float inv = 1.0f / sqrtf(var + 1e-5f);
    z = (z - mu) * inv * gamma[m * P_ + p] + beta[m * P_ + p];

    // L2 norm across row g
    float s = z * z;
    for (int off = 32; off > 0; off >>= 1) s += __shfl_xor(s, off);
    if (lane == 0) redC[g][w] = s;
    __syncthreads();
    s = (redC[g][0] + redC[g][1]) + (redC[g][2] + redC[g][3]);
    float n = sqrtf(s);
    out[((size_t)m * B_ + b0 + g) * P_ + p] = z / fmaxf(n, 1e-12f);
}

extern "C" void kernel_launch(void* const* d_in, const int* in_sizes, int n_in,
                              void* d_out, int out_size, void* d_ws, size_t ws_size,
                              hipStream_t stream) {
    const float* feats = (const float*)d_in[0];
    const float* W1    = (const float*)d_in[1];
    const float* b1    = (const float*)d_in[2];
    const float* W2    = (const float*)d_in[3];
    const float* b2    = (const float*)d_in[4];
    const float* gamma = (const float*)d_in[5];
    const float* beta  = (const float*)d_in[6];
    float* out = (float*)d_out;

    float* wsf = (float*)d_ws;
    float*        partial = wsf;                                    // M*B*TC*D = 786432 floats
    unsigned int* w2p     = (unsigned int*)(wsf + 786432);          // M*(D/2)*P = 393216 u32
    float*        hbuf    = wsf + 786432 + 393216;                  // M*B*D = 393216 floats
    // total ws: 6 MB

    pool_and_cast<<<NRIDER + M_ * B_ * TC, 256, 0, stream>>>(feats, W2, partial, w2p);
    dim3 g2(D_ / BN1, B_ / BM1, M_);
    gemm1_gelu<<<g2, 512, 0, stream>>>(partial, W1, b1, hbuf);
    dim3 g3(B_ / 2, M_);
    gemm2_ln<<<g3, 512, 0, stream>>>(hbuf, w2p, b2, gamma, beta, out);
}